// Round 21
// baseline (81.568 us; speedup 1.0000x reference)
//
#include <hip/hip_runtime.h>
#include <hip/hip_bf16.h>

using f32x4 = __attribute__((ext_vector_type(4))) float;
using s16x8 = __attribute__((ext_vector_type(8))) short;
using u32x4 = __attribute__((ext_vector_type(4))) unsigned;

// Problem dims (fixed by reference setup_inputs)
constexpr int Bn = 4, Cc = 32, Hh = 256, Ww = 256;
constexpr int H2 = 128, W2 = 128;
constexpr int NF = 128;                 // KAN feature dim (= W2)
constexpr int KTOT = 1152;              // 128 features x 9 (silu + 8 bases)

// ---- bf16 round-to-nearest-even ----
__device__ __forceinline__ short f2bf(float f) {
    union { float f; unsigned u; } v; v.f = f;
    unsigned r = v.u + 0x7fffu + ((v.u >> 16) & 1u);
    return (short)(r >> 16);
}

// hardware bf16 pair pack (v_cvt_pk_bf16_f32)
__device__ __forceinline__ unsigned pk_bf16(float a, float b) {
    union { __hip_bfloat162 h; unsigned u; } c;
    c.h.x = __float2bfloat16(a);
    c.h.y = __float2bfloat16(b);
    return c.u;
}

// direct HBM/L2 -> LDS, 16B per lane, no VGPR round-trip
__device__ __forceinline__ void gload_lds16(const void* g, void* l) {
    __builtin_amdgcn_global_load_lds(
        (const __attribute__((address_space(1))) unsigned*)g,
        (__attribute__((address_space(3))) unsigned*)l, 16, 0, 0);
}

// Place [wD,wC,wB,wA] (bf16-packed u64) at slot (ci-3) of an 8-slot 128-bit
// window; slots outside [0,7] dropped. ci guaranteed in [0,10] by caller.
__device__ __forceinline__ void window128(float wD, float wC, float wB, float wA,
                                          int ci, unsigned W[4]) {
    unsigned long long P = ((unsigned long long)pk_bf16(wB, wA) << 32)
                         | (unsigned long long)pk_bf16(wD, wC);
    int sh = ci * 16 - 48;
    unsigned long long sl = P << (sh & 63);
    unsigned long long sr = P >> ((-sh) & 63);
    unsigned long long lo = (sh < 0) ? sr : ((sh < 64) ? sl : 0ull);
    int shh = sh - 64;
    unsigned long long sl2 = P << (shh & 63);
    unsigned long long sr2 = P >> ((-shh) & 63);
    unsigned long long hi = (shh >= 0) ? sl2 : (((-shh) < 64) ? sr2 : 0ull);
    W[0] = (unsigned)lo; W[1] = (unsigned)(lo >> 32);
    W[2] = (unsigned)hi; W[3] = (unsigned)(hi >> 32);
}

// ---- KW: bf16 weight matrix in MFMA-FRAGMENT order (into d_ws) ----
// Bg[tile][lane][q], tile = (ni*4 + jg)*9 + ks  (ni:8, jg:4, ks:9 -> 288 tiles)
__global__ __launch_bounds__(256) void k_wbuild(const float* __restrict__ base_w,
                                                const float* __restrict__ spline_w,
                                                const float* __restrict__ scaler,
                                                short* __restrict__ Bg) {
    int idx = blockIdx.x * 256 + threadIdx.x;   // 147456 total
    int tile = idx >> 9;
    int r = idx & 511;
    int lane = r >> 3, q = r & 7;
    int ni = tile / 36; int rem = tile - ni * 36;
    int jg = rem / 9;   int ks = rem - jg * 9;
    int o = ni * 16 + (lane & 15);
    int kk = ks * 32 + (lane >> 4) * 8 + q;
    int g = kk >> 5, jl = kk & 31;
    int j = jg * 32 + jl;
    float v = (g == 0) ? base_w[o * NF + j]
                       : spline_w[(long)(o * NF + j) * 8 + (g - 1)] * scaler[o * NF + j];
    Bg[idx] = f2bf(v);
}

// ---- MEGA kernel, mi-split + half-chunk double-buffered B schedule ----
// block = 512 thr = 8 waves = (plane, 32-row band); wave = (kcomp, mi-half).
// Per half-chunk region: one barrier, {issue next stage -> MFMA -> expansion}.
// No expansion/MFMA barrier -> waves pipeline LDS and VALU phases.
__global__ __launch_bounds__(512, 4) void k_fused(const float* __restrict__ x,
                                                  const float* __restrict__ cw,
                                                  const float* __restrict__ cb,
                                                  float* __restrict__ out,
                                                  const short* __restrict__ Bg) {
    __shared__ __align__(16) short Bsh[2][36 * 512];    // 2 x 36 KB
    const int t = threadIdx.x;
    const int lane = t & 63;
    const int wv = t >> 6;                      // wave id 0..7
    const int kcomp = wv & 3;                   // Haar component
    const int mih = wv >> 2;                    // row half 0,1
    const int blk = blockIdx.x;                 // plane*4 + band
    const int plane = blk >> 2;
    const int band = blk & 3;
    const int i0 = band << 5;                   // 32 i-rows per block
    const int jg0 = blk & 3;                    // stagger start jg
    const int il = lane & 15;                   // i_local within 16-tile
    const int fg = lane >> 4;                   // k-subslice 0..3

    // Haar signs for this wave's kcomp
    const float sB = (kcomp & 2) ? -1.f : 1.f;
    const float sC = (kcomp & 1) ? -1.f : 1.f;
    const float sD = sB * sC;

    const float* xbase = x + (long)plane * Hh * Ww;
    const float* xr0 = xbase + (long)(2 * (i0 + mih * 16 + il)) * Ww;
    const float* xr1 = xr0 + Ww;

    u32x4 afr[9];                               // A-fragments [g] (one jg)

    // expansion for one jg (register-only)
    auto expansion = [&](int jg) {
        const int cb2 = jg * 64 + fg * 16;
#pragma unroll
        for (int p = 0; p < 4; ++p) {           // feature pairs
            f32x4 va = *(const f32x4*)(xr0 + cb2 + 4 * p);
            f32x4 vb = *(const f32x4*)(xr1 + cb2 + 4 * p);
            float vv[2];
            vv[0] = 0.5f * (va[0] + sB * va[1] + sC * vb[0] + sD * vb[1]);
            vv[1] = 0.5f * (va[2] + sB * va[3] + sC * vb[2] + sD * vb[3]);
            float sl2[2]; unsigned Wf[2][4];
#pragma unroll
            for (int e = 0; e < 2; ++e) {
                float v = vv[e];
                float ex = __builtin_amdgcn_exp2f(-1.442695040888963f * v);
                sl2[e] = v * __builtin_amdgcn_rcpf(1.0f + ex);      // silu
                float xs = __builtin_fmaf(v, 2.5f, 5.5f);           // (v+2.2)*2.5
                xs = fminf(fmaxf(xs, 0.0f), 10.999f);               // med3 clamp
                float cf = floorf(xs);
                float u = xs - cf;
                int ci = (int)cf;                                   // 0..10
                float u2 = u * u, u3 = u2 * u;
                float wA = u3 * (1.f / 6.f);
                float wB = (1.f + 3.f * u + 3.f * u2 - 3.f * u3) * (1.f / 6.f);
                float wC = (4.f - 6.f * u2 + 3.f * u3) * (1.f / 6.f);
                float um = 1.f - u;
                float wD = um * um * um * (1.f / 6.f);
                window128(wD, wC, wB, wA, ci, Wf[e]);
            }
            afr[0][p] = pk_bf16(sl2[0], sl2[1]);
#pragma unroll
            for (int g = 1; g <= 8; ++g) {
                int wq = (g - 1) >> 1;
                unsigned sel = ((g - 1) & 1) ? 0x07060302u : 0x05040100u;
                afr[g][p] = __builtin_amdgcn_perm(Wf[1][wq], Wf[0][wq], sel);
            }
        }
    };

    // issue 36-tile stage for (jg, nh) into Bsh[buf]
    auto stage_issue = [&](int jg, int nh, int buf) {
#pragma unroll
        for (int i = 0; i < 5; ++i) {
            int q = i * 8 + wv;                 // 0..39; tiles 0..35 valid
            if (q < 36) {
                int nl = q / 9, ks = q - nl * 9;
                int ng = nh * 4 + nl;           // global ni
                gload_lds16(&Bg[(long)(((ng * 4 + jg) * 9 + ks) << 9) + lane * 8],
                            &Bsh[buf][q << 9]);
            }
        }
    };

    f32x4 acc[8];
#pragma unroll
    for (int ni = 0; ni < 8; ++ni)
        acc[ni] = (f32x4){0.f, 0.f, 0.f, 0.f};

    // prologue: stage first half-chunk; expansion covers its latency
    stage_issue(jg0, 0, 0);
    expansion(jg0);

    for (int s = 0; s < 8; ++s) {               // s = jg_step*2 + nh
        const int nh = s & 1;
        __syncthreads();                        // buf(s&1) staged & prior reads done
        if (s < 7) {
            const int s1 = s + 1;
            stage_issue((jg0 + (s1 >> 1)) & 3, s1 & 1, s1 & 1);
        }
        // MFMA half-sweep: 9 ks x 4 nl from buf(s&1)
#pragma unroll
        for (int ks = 0; ks < 9; ++ks) {
            s16x8 bfr[4];
#pragma unroll
            for (int nl = 0; nl < 4; ++nl)
                bfr[nl] = *(const s16x8*)&Bsh[s & 1][((nl * 9 + ks) << 9) + lane * 8];
            s16x8 a = __builtin_bit_cast(s16x8, afr[ks]);
#pragma unroll
            for (int nl = 0; nl < 4; ++nl)
                acc[nh * 4 + nl] = __builtin_amdgcn_mfma_f32_16x16x32_bf16(
                    a, bfr[nl], acc[nh * 4 + nl], 0, 0, 0);
        }
        // after the 2nd half of a jg, compute next jg's expansion (afr free)
        if ((s & 1) && s < 7) expansion((jg0 + (s >> 1) + 1) & 3);
    }

    // ---- z exchange through LDS (Bsh reused): zsh[kcomp*32+row][132] ----
    __syncthreads();                            // all buf reads done
    constexpr int ZP = 132;                     // padded stride -> 2-way banks
    float* zsh = (float*)Bsh;                   // 4*32*132*4B = 67.6 KB <= 72 KB
#pragma unroll
    for (int rr = 0; rr < 4; ++rr)
#pragma unroll
        for (int ni = 0; ni < 8; ++ni)
            zsh[(kcomp * 32 + mih * 16 + fg * 4 + rr) * ZP + ni * 16 + il]
                = acc[ni][rr];
    __syncthreads();

    // ---- conv(5x5) + bias + inverse Haar + write final out ----
    const int c = plane & 31;
    float cwr[25];
#pragma unroll
    for (int q = 0; q < 25; ++q) cwr[q] = cw[c * 25 + q];
    const float bias = cb[c];
    float* outp = out + (long)plane * Hh * Ww;

#pragma unroll
    for (int qxh = 0; qxh < 2; ++qxh) {
        const int jq = qxh * 64 + lane;         // quad col 0..127
        const float mlo = (jq >= 1) ? 1.f : 0.f;
        const float mhi = (jq <= 126) ? 1.f : 0.f;
        const int clo = (jq >= 1) ? (2 * jq - 2) : 0;
        const int cmid = 2 * jq;
        const int chi = (jq <= 126) ? (2 * jq + 2) : 252;
        float xv[6][6];
#pragma unroll
        for (int a = 0; a < 4; ++a) {
            const int ql = wv * 4 + a;          // local quad row 0..31
            const int orow = 2 * (i0 + ql);     // global out row (even)
            const int rlo = (a == 0) ? 0 : 4;
            if (a) {                            // roll window down by 2 rows
#pragma unroll
                for (int r6 = 0; r6 < 4; ++r6)
#pragma unroll
                    for (int c6 = 0; c6 < 6; ++c6) xv[r6][c6] = xv[r6 + 2][c6];
            }
#pragma unroll
            for (int r6 = 0; r6 < 6; ++r6) {
                if (r6 < rlo) continue;
                int xr = orow - 2 + r6;
                int xrc = min(max(xr, 0), Hh - 1);
                float mrow = (xr >= 0 && xr < Hh) ? 1.f : 0.f;
                const float* xrp = xbase + (long)xrc * Ww;
                float2 lo = *(const float2*)(xrp + clo);
                float2 mi2 = *(const float2*)(xrp + cmid);
                float2 hi = *(const float2*)(xrp + chi);
                float ml = mlo * mrow, mh = mhi * mrow;
                xv[r6][0] = lo.x * ml;    xv[r6][1] = lo.y * ml;
                xv[r6][2] = mi2.x * mrow; xv[r6][3] = mi2.y * mrow;
                xv[r6][4] = hi.x * mh;    xv[r6][5] = hi.y * mh;
            }
            // inverse Haar from LDS
            float z0 = zsh[(ql) * ZP + jq];
            float z1 = zsh[(32 + ql) * ZP + jq];
            float z2 = zsh[(64 + ql) * ZP + jq];
            float z3 = zsh[(96 + ql) * ZP + jq];
            float y00 = 0.5f * (z0 + z1 + z2 + z3);
            float y01 = 0.5f * (z0 + z1 - z2 - z3);
            float y10 = 0.5f * (z0 - z1 + z2 - z3);
            float y11 = 0.5f * (z0 - z1 - z2 + z3);
            // 2x2 conv outputs + skip add
            float s00 = bias, s01 = bias, s10 = bias, s11 = bias;
#pragma unroll
            for (int ky = 0; ky < 5; ++ky)
#pragma unroll
                for (int kx = 0; kx < 5; ++kx) {
                    float wv2 = cwr[ky * 5 + kx];
                    s00 += wv2 * xv[ky][kx];
                    s01 += wv2 * xv[ky][kx + 1];
                    s10 += wv2 * xv[ky + 1][kx];
                    s11 += wv2 * xv[ky + 1][kx + 1];
                }
            float* op = outp + (long)orow * Ww + 2 * jq;
            *(float2*)op        = make_float2(s00 + y00, s01 + y01);
            *(float2*)(op + Ww) = make_float2(s10 + y10, s11 + y11);
        }
    }
}

extern "C" void kernel_launch(void* const* d_in, const int* in_sizes, int n_in,
                              void* d_out, int out_size, void* d_ws, size_t ws_size,
                              hipStream_t stream) {
    const float* x        = (const float*)d_in[0];
    const float* conv_w   = (const float*)d_in[1];
    const float* conv_b   = (const float*)d_in[2];
    const float* base_w   = (const float*)d_in[3];
    const float* spline_w = (const float*)d_in[4];
    const float* scaler   = (const float*)d_in[5];
    float* out = (float*)d_out;
    short* Bg  = (short*)d_ws;              // 288 KB fragment-order weights in ws

    // 1) fragment-order bf16 weights into ws
    k_wbuild<<<(NF * KTOT) / 256, 256, 0, stream>>>(base_w, spline_w, scaler, Bg);
    // 2) mi-split, half-chunk double-buffered pipeline (512 blocks x 512 thr)
    k_fused<<<512, 512, 0, stream>>>(x, conv_w, conv_b, out, Bg);
}

// Round 22
// 54.450 us; speedup vs baseline: 1.4980x; 1.4980x over previous
//
#include <hip/hip_runtime.h>
#include <hip/hip_bf16.h>

using f32x4 = __attribute__((ext_vector_type(4))) float;
using s16x8 = __attribute__((ext_vector_type(8))) short;
using u32x4 = __attribute__((ext_vector_type(4))) unsigned;

// Problem dims (fixed by reference setup_inputs)
constexpr int Bn = 4, Cc = 32, Hh = 256, Ww = 256;
constexpr int H2 = 128, W2 = 128;
constexpr int NF = 128;                 // KAN feature dim (= W2)
constexpr int KTOT = 1152;              // 128 features x 9 (silu + 8 bases)

// ---- bf16 round-to-nearest-even ----
__device__ __forceinline__ short f2bf(float f) {
    union { float f; unsigned u; } v; v.f = f;
    unsigned r = v.u + 0x7fffu + ((v.u >> 16) & 1u);
    return (short)(r >> 16);
}

// hardware bf16 pair pack (v_cvt_pk_bf16_f32)
__device__ __forceinline__ unsigned pk_bf16(float a, float b) {
    union { __hip_bfloat162 h; unsigned u; } c;
    c.h.x = __float2bfloat16(a);
    c.h.y = __float2bfloat16(b);
    return c.u;
}

// direct HBM/L2 -> LDS, 16B per lane, no VGPR round-trip
__device__ __forceinline__ void gload_lds16(const void* g, void* l) {
    __builtin_amdgcn_global_load_lds(
        (const __attribute__((address_space(1))) unsigned*)g,
        (__attribute__((address_space(3))) unsigned*)l, 16, 0, 0);
}

// Place [wD,wC,wB,wA] (bf16-packed u64) at slot (ci-3) of an 8-slot 128-bit
// window; slots outside [0,7] dropped. ci guaranteed in [0,10] by caller.
__device__ __forceinline__ void window128(float wD, float wC, float wB, float wA,
                                          int ci, unsigned W[4]) {
    unsigned long long P = ((unsigned long long)pk_bf16(wB, wA) << 32)
                         | (unsigned long long)pk_bf16(wD, wC);
    int sh = ci * 16 - 48;
    unsigned long long sl = P << (sh & 63);
    unsigned long long sr = P >> ((-sh) & 63);
    unsigned long long lo = (sh < 0) ? sr : ((sh < 64) ? sl : 0ull);
    int shh = sh - 64;
    unsigned long long sl2 = P << (shh & 63);
    unsigned long long sr2 = P >> ((-shh) & 63);
    unsigned long long hi = (shh >= 0) ? sl2 : (((-shh) < 64) ? sr2 : 0ull);
    W[0] = (unsigned)lo; W[1] = (unsigned)(lo >> 32);
    W[2] = (unsigned)hi; W[3] = (unsigned)(hi >> 32);
}

// ---- KW: bf16 weight matrix in MFMA-FRAGMENT order (into d_ws) ----
// Bg[tile][lane][q], tile = (ni*4 + jg)*9 + ks  (ni:8, jg:4, ks:9 -> 288 tiles)
__global__ __launch_bounds__(256) void k_wbuild(const float* __restrict__ base_w,
                                                const float* __restrict__ spline_w,
                                                const float* __restrict__ scaler,
                                                short* __restrict__ Bg) {
    int idx = blockIdx.x * 256 + threadIdx.x;   // 147456 total
    int tile = idx >> 9;
    int r = idx & 511;
    int lane = r >> 3, q = r & 7;
    int ni = tile / 36; int rem = tile - ni * 36;
    int jg = rem / 9;   int ks = rem - jg * 9;
    int o = ni * 16 + (lane & 15);
    int kk = ks * 32 + (lane >> 4) * 8 + q;
    int g = kk >> 5, jl = kk & 31;
    int j = jg * 32 + jl;
    float v = (g == 0) ? base_w[o * NF + j]
                       : spline_w[(long)(o * NF + j) * 8 + (g - 1)] * scaler[o * NF + j];
    Bg[idx] = f2bf(v);
}

// ---- MEGA kernel, mi-split: Haar + expand + MFMA KAN + invHaar + conv ----
// block = 512 thr = 8 waves = (plane, 32-row band); wave = (kcomp, mi-half).
// 4 waves/SIMD resident (2 blocks/CU), no duplicated expansion, no spill.
// (r19 configuration: best measured. Overlap variants r17/r18/r20/r21 all
// regressed via spill or duplicated work -- see session journal.)
__global__ __launch_bounds__(512, 4) void k_fused(const float* __restrict__ x,
                                                  const float* __restrict__ cw,
                                                  const float* __restrict__ cb,
                                                  float* __restrict__ out,
                                                  const short* __restrict__ Bg) {
    __shared__ __align__(16) short Bsh[72 * 512];   // 72 KB (B stage / z tile)
    const int t = threadIdx.x;
    const int lane = t & 63;
    const int wv = t >> 6;                      // wave id 0..7
    const int kcomp = wv & 3;                   // Haar component
    const int mih = wv >> 2;                    // row half 0,1
    const int blk = blockIdx.x;                 // plane*4 + band
    const int plane = blk >> 2;
    const int band = blk & 3;
    const int i0 = band << 5;                   // 32 i-rows per block
    const int jg0 = blk & 3;                    // stagger start jg
    const int il = lane & 15;                   // i_local within 16-tile
    const int fg = lane >> 4;                   // k-subslice 0..3

    // Haar signs for this wave's kcomp
    const float sB = (kcomp & 2) ? -1.f : 1.f;
    const float sC = (kcomp & 1) ? -1.f : 1.f;
    const float sD = sB * sC;

    const float* xbase = x + (long)plane * Hh * Ww;
    const float* xr0 = xbase + (long)(2 * (i0 + mih * 16 + il)) * Ww;
    const float* xr1 = xr0 + Ww;

    f32x4 acc[8];
#pragma unroll
    for (int ni = 0; ni < 8; ++ni)
        acc[ni] = (f32x4){0.f, 0.f, 0.f, 0.f};

    for (int j = 0; j < 4; ++j) {
        const int jg = (jg0 + j) & 3;
        const int cb2 = jg * 64 + fg * 16;      // x column base (16 floats)

        // --- issue B stage via global_load_lds (wave wv -> tiles s*8+wv) ---
#pragma unroll
        for (int s = 0; s < 9; ++s) {
            int q = s * 8 + wv;                 // LDS tile 0..71 (= nl*9+ks)
            int nl = q / 9, ks = q - nl * 9;
            gload_lds16(&Bg[(long)(((nl * 4 + jg) * 9 + ks) << 9) + lane * 8],
                        &Bsh[q << 9]);
        }

        u32x4 afr[9];                           // A-fragments [g] (one mi)
        // --- expansion (register-only; covers stage-load latency) ---
#pragma unroll
        for (int p = 0; p < 4; ++p) {           // feature pairs
            f32x4 va = *(const f32x4*)(xr0 + cb2 + 4 * p);
            f32x4 vb = *(const f32x4*)(xr1 + cb2 + 4 * p);
            float vv[2];
            vv[0] = 0.5f * (va[0] + sB * va[1] + sC * vb[0] + sD * vb[1]);
            vv[1] = 0.5f * (va[2] + sB * va[3] + sC * vb[2] + sD * vb[3]);
            float sl2[2]; unsigned Wf[2][4];
#pragma unroll
            for (int e = 0; e < 2; ++e) {
                float v = vv[e];
                float ex = __builtin_amdgcn_exp2f(-1.442695040888963f * v);
                sl2[e] = v * __builtin_amdgcn_rcpf(1.0f + ex);      // silu
                float xs = __builtin_fmaf(v, 2.5f, 5.5f);           // (v+2.2)*2.5
                xs = fminf(fmaxf(xs, 0.0f), 10.999f);               // med3 clamp
                float cf = floorf(xs);
                float u = xs - cf;
                int ci = (int)cf;                                   // 0..10
                float u2 = u * u, u3 = u2 * u;
                float wA = u3 * (1.f / 6.f);
                float wB = (1.f + 3.f * u + 3.f * u2 - 3.f * u3) * (1.f / 6.f);
                float wC = (4.f - 6.f * u2 + 3.f * u3) * (1.f / 6.f);
                float um = 1.f - u;
                float wD = um * um * um * (1.f / 6.f);
                window128(wD, wC, wB, wA, ci, Wf[e]);
            }
            afr[0][p] = pk_bf16(sl2[0], sl2[1]);
#pragma unroll
            for (int g = 1; g <= 8; ++g) {
                int wq = (g - 1) >> 1;
                unsigned sel = ((g - 1) & 1) ? 0x07060302u : 0x05040100u;
                afr[g][p] = __builtin_amdgcn_perm(Wf[1][wq], Wf[0][wq], sel);
            }
        }

        __syncthreads();                        // vmcnt drained: B(jg) in LDS

        // --- MFMA sweep from LDS: 9 ks x 8 ni (one mi) ---
#pragma unroll
        for (int ks = 0; ks < 9; ++ks) {
            s16x8 bfr[8];
#pragma unroll
            for (int ni = 0; ni < 8; ++ni)
                bfr[ni] = *(const s16x8*)&Bsh[((ni * 9 + ks) << 9) + lane * 8];
            s16x8 a = __builtin_bit_cast(s16x8, afr[ks]);
#pragma unroll
            for (int ni = 0; ni < 8; ++ni)
                acc[ni] = __builtin_amdgcn_mfma_f32_16x16x32_bf16(
                    a, bfr[ni], acc[ni], 0, 0, 0);
        }
        __syncthreads();                        // all B(jg) reads done
    }

    // ---- z exchange through LDS (Bsh reused): zsh[kcomp*32+row][132] ----
    constexpr int ZP = 132;                     // padded stride -> 2-way banks
    float* zsh = (float*)Bsh;                   // 4*32*132*4B = 67.6 KB
#pragma unroll
    for (int rr = 0; rr < 4; ++rr)
#pragma unroll
        for (int ni = 0; ni < 8; ++ni)
            zsh[(kcomp * 32 + mih * 16 + fg * 4 + rr) * ZP + ni * 16 + il]
                = acc[ni][rr];
    __syncthreads();

    // ---- conv(5x5) + bias + inverse Haar + write final out ----
    const int c = plane & 31;
    float cwr[25];
#pragma unroll
    for (int q = 0; q < 25; ++q) cwr[q] = cw[c * 25 + q];
    const float bias = cb[c];
    float* outp = out + (long)plane * Hh * Ww;

#pragma unroll
    for (int qxh = 0; qxh < 2; ++qxh) {
        const int jq = qxh * 64 + lane;         // quad col 0..127
        const float mlo = (jq >= 1) ? 1.f : 0.f;
        const float mhi = (jq <= 126) ? 1.f : 0.f;
        const int clo = (jq >= 1) ? (2 * jq - 2) : 0;
        const int cmid = 2 * jq;
        const int chi = (jq <= 126) ? (2 * jq + 2) : 252;
        float xv[6][6];
#pragma unroll
        for (int a = 0; a < 4; ++a) {
            const int ql = wv * 4 + a;          // local quad row 0..31
            const int orow = 2 * (i0 + ql);     // global out row (even)
            const int rlo = (a == 0) ? 0 : 4;
            if (a) {                            // roll window down by 2 rows
#pragma unroll
                for (int r6 = 0; r6 < 4; ++r6)
#pragma unroll
                    for (int c6 = 0; c6 < 6; ++c6) xv[r6][c6] = xv[r6 + 2][c6];
            }
#pragma unroll
            for (int r6 = 0; r6 < 6; ++r6) {
                if (r6 < rlo) continue;
                int xr = orow - 2 + r6;
                int xrc = min(max(xr, 0), Hh - 1);
                float mrow = (xr >= 0 && xr < Hh) ? 1.f : 0.f;
                const float* xrp = xbase + (long)xrc * Ww;
                float2 lo = *(const float2*)(xrp + clo);
                float2 mi2 = *(const float2*)(xrp + cmid);
                float2 hi = *(const float2*)(xrp + chi);
                float ml = mlo * mrow, mh = mhi * mrow;
                xv[r6][0] = lo.x * ml;    xv[r6][1] = lo.y * ml;
                xv[r6][2] = mi2.x * mrow; xv[r6][3] = mi2.y * mrow;
                xv[r6][4] = hi.x * mh;    xv[r6][5] = hi.y * mh;
            }
            // inverse Haar from LDS
            float z0 = zsh[(ql) * ZP + jq];
            float z1 = zsh[(32 + ql) * ZP + jq];
            float z2 = zsh[(64 + ql) * ZP + jq];
            float z3 = zsh[(96 + ql) * ZP + jq];
            float y00 = 0.5f * (z0 + z1 + z2 + z3);
            float y01 = 0.5f * (z0 + z1 - z2 - z3);
            float y10 = 0.5f * (z0 - z1 + z2 - z3);
            float y11 = 0.5f * (z0 - z1 - z2 + z3);
            // 2x2 conv outputs + skip add
            float s00 = bias, s01 = bias, s10 = bias, s11 = bias;
#pragma unroll
            for (int ky = 0; ky < 5; ++ky)
#pragma unroll
                for (int kx = 0; kx < 5; ++kx) {
                    float wv2 = cwr[ky * 5 + kx];
                    s00 += wv2 * xv[ky][kx];
                    s01 += wv2 * xv[ky][kx + 1];
                    s10 += wv2 * xv[ky + 1][kx];
                    s11 += wv2 * xv[ky + 1][kx + 1];
                }
            float* op = outp + (long)orow * Ww + 2 * jq;
            *(float2*)op        = make_float2(s00 + y00, s01 + y01);
            *(float2*)(op + Ww) = make_float2(s10 + y10, s11 + y11);
        }
    }
}

extern "C" void kernel_launch(void* const* d_in, const int* in_sizes, int n_in,
                              void* d_out, int out_size, void* d_ws, size_t ws_size,
                              hipStream_t stream) {
    const float* x        = (const float*)d_in[0];
    const float* conv_w   = (const float*)d_in[1];
    const float* conv_b   = (const float*)d_in[2];
    const float* base_w   = (const float*)d_in[3];
    const float* spline_w = (const float*)d_in[4];
    const float* scaler   = (const float*)d_in[5];
    float* out = (float*)d_out;
    short* Bg  = (short*)d_ws;              // 288 KB fragment-order weights in ws

    // 1) fragment-order bf16 weights into ws
    k_wbuild<<<(NF * KTOT) / 256, 256, 0, stream>>>(base_w, spline_w, scaler, Bg);
    // 2) mi-split fully-fused pipeline -> final out (512 blocks x 512 thr)
    k_fused<<<512, 512, 0, stream>>>(x, conv_w, conv_b, out, Bg);
}